// Round 6
// baseline (113.697 us; speedup 1.0000x reference)
//
#include <hip/hip_runtime.h>
#include <math.h>

// Problem constants (from the reference):
//  levels: (64,64,s=8,bs=32) (32,32,s=16,bs=64) (16,16,s=32,bs=128) (8,8,s=64,bs=256)
//  K = 9 anchors/position (3 ratios x 3 scales), A = 48960, B = 16, M = 64 GT boxes
// Level boundaries 36864/46080/48384 are multiples of 64 -> every wave is
// single-level and every wave's 64 anchors share one bounding window.
#define A_TOTAL 48960
#define N_WAVES (A_TOTAL / 64)   // 765
#define M_GT    64
#define B_BATCH 16
#define B_PER_BLK 4              // batches per block (amortize anchor-fixed cost)

// ---- prep: batch-invariant per-anchor + per-wave data, computed once ----
// rec[a] = {acx, acy, aw, ah}; rin[a] = {1/(aw*.1), 1/(ah*.1), 1/aw, 1/ah};
// win[w] = {wx1, wy1, wx2, wy2} (exact per-wave bounding window)
__global__ __launch_bounds__(256) void prep_kernel(
    float4* __restrict__ rec, float4* __restrict__ rin, float4* __restrict__ win)
{
    const int a = blockIdx.x * 256 + threadIdx.x;
    if (a >= A_TOTAL) return;

    int local, W, stride, bs;
    if (a < 36864)      { local = a;         W = 64; stride = 8;  bs = 32;  }
    else if (a < 46080) { local = a - 36864; W = 32; stride = 16; bs = 64;  }
    else if (a < 48384) { local = a - 46080; W = 16; stride = 32; bs = 128; }
    else                { local = a - 48384; W = 8;  stride = 64; bs = 256; }

    const int hw = local / 9;
    const int k  = local - hw * 9;
    const int y  = hw / W;
    const int x  = hw - y * W;
    const int r  = k / 3;
    const int s  = k - r * 3;

    // anchor w/h in double, exactly mirroring numpy's op order
    const double sc = (s == 0) ? 1.0 : ((s == 1) ? 1.2599210498948732   // 2^(1/3)
                                                 : 1.5874010519681994); // 2^(2/3)
    const double rr = (r == 0) ? 0.5 : ((r == 1) ? 1.0 : 2.0);
    const double av   = (double)bs * sc;
    const double area = av * av;
    const double wd   = sqrt(area * rr);
    const double hd   = wd / rr;
    const float aw = (float)wd, ah = (float)hd;

    const float acx = ((float)x + 0.5f) * (float)stride;
    const float acy = ((float)y + 0.5f) * (float)stride;
    const float hx = aw * 0.5f, hy = ah * 0.5f;      // exact (*2^-1)
    const float ax1 = acx - hx, ay1 = acy - hy;
    const float ax2 = acx + hx, ay2 = acy + hy;

    rec[a] = make_float4(acx, acy, aw, ah);
    rin[a] = make_float4(1.0f / (aw * 0.1f), 1.0f / (ah * 0.1f),
                         1.0f / aw,          1.0f / ah);

    float wx1 = ax1, wy1 = ay1, wx2 = ax2, wy2 = ay2;
    #pragma unroll
    for (int m = 1; m < 64; m <<= 1) {
        wx1 = fminf(wx1, __shfl_xor(wx1, m, 64));
        wy1 = fminf(wy1, __shfl_xor(wy1, m, 64));
        wx2 = fmaxf(wx2, __shfl_xor(wx2, m, 64));
        wy2 = fmaxf(wy2, __shfl_xor(wy2, m, 64));
    }
    if ((threadIdx.x & 63) == 0) win[a >> 6] = make_float4(wx1, wy1, wx2, wy2);
}

__global__ __launch_bounds__(256) void anchors_assign_kernel(
    const float*  __restrict__ gt_boxes,   // (B, 64, 4) xyxy
    const int*    __restrict__ gt_labels,  // (B, 64)
    const float4* __restrict__ rec,
    const float4* __restrict__ rin,
    const float4* __restrict__ win,
    float* __restrict__ out_loc,           // (B, A, 4)
    float* __restrict__ out_cls)           // (B, A)
{
    __shared__ float4 sbox[B_PER_BLK][M_GT];
    __shared__ float  sarea[B_PER_BLK][M_GT];
    __shared__ float  slab[B_PER_BLK][M_GT];

    const int b0  = blockIdx.y * B_PER_BLK;
    const int tid = threadIdx.x;

    // Stage 4 batches' GT: thread t -> batch t>>6, box t&63 (coalesced float4)
    {
        const int bb = tid >> 6, j = tid & 63;
        const float4 g = ((const float4*)gt_boxes)[(b0 + bb) * M_GT + j];
        sbox[bb][j]  = g;
        sarea[bb][j] = (g.z - g.x) * (g.w - g.y);   // same op order as ref
        slab[bb][j]  = (float)gt_labels[(b0 + bb) * M_GT + j];
    }
    __syncthreads();

    const int a = blockIdx.x * 256 + tid;
    if (a >= A_TOTAL) return;   // tail is whole waves, after the barrier

    // batch-invariant anchor data, loaded ONCE for all 4 batches
    const float4 rc = rec[a];
    const float4 ri = rin[a];
    const float4 wv = win[a >> 6];          // wave-uniform address -> 1 line

    const float acx = rc.x, acy = rc.y, aw = rc.z, ah = rc.w;
    const float hx = aw * 0.5f, hy = ah * 0.5f;    // bit-identical reconstruction
    const float ax1 = acx - hx, ay1 = acy - hy;
    const float ax2 = acx + hx, ay2 = acy + hy;
    const float areaA = (ax2 - ax1) * (ay2 - ay1); // ref recomputes from xyxy

    const int lane = tid & 63;

    #pragma unroll
    for (int bb = 0; bb < B_PER_BLK; ++bb) {
        // candidate mask: lane j tests GT box j against the wave window.
        // Edge-touching boxes give inter==0 for every anchor in the wave ->
        // safe to prune (0-iou can't beat b_inter=0 init; all-pruned case
        // yields bidx=0 = np.argmax of all-zero row).
        const float4 gb = sbox[bb][lane];
        const bool cand = (fminf(wv.z, gb.z) > fmaxf(wv.x, gb.x)) &&
                          (fminf(wv.w, gb.w) > fmaxf(wv.y, gb.y));
        unsigned long long mask = __ballot(cand);   // wave-uniform

        // division-free IoU argmax over candidates, ascending j (first max,
        // matching np.argmax). Software-pipelined: next candidate's LDS load
        // is issued before the current compare chain consumes its data.
        float b_inter = 0.0f, b_den = 1.0f;
        int   bidx = 0;
        if (mask) {
            int j = (int)__builtin_ctzll(mask);
            mask &= mask - 1;
            float4 g  = sbox[bb][j];
            float  ga = sarea[bb][j];
            while (true) {
                int jn = -1; float4 gn; float gan = 0.0f;
                if (mask) {                         // uniform branch
                    jn = (int)__builtin_ctzll(mask);
                    mask &= mask - 1;
                    gn  = sbox[bb][jn];             // prefetch next candidate
                    gan = sarea[bb][jn];
                }
                const float ltx = fmaxf(ax1, g.x), lty = fmaxf(ay1, g.y);
                const float rbx = fminf(ax2, g.z), rby = fminf(ay2, g.w);
                const float wx = fmaxf(rbx - ltx, 0.0f);
                const float wy = fmaxf(rby - lty, 0.0f);
                const float inter = wx * wy;
                const float den   = (areaA + ga) - inter;   // same assoc as ref
                if (inter * b_den > b_inter * den) {        // iou_j > iou_best
                    b_inter = inter; b_den = den; bidx = j;
                }
                if (jn < 0) break;
                j = jn; g = gn; ga = gan;
            }
        }
        const float best = b_inter / b_den;   // exact IEEE: bit-matches ref iou

        // label thresholding (order matches ref: ign first, bg overrides)
        float lab = slab[bb][bidx];
        if (best > 0.4f && best < 0.5f) lab = -1.0f;
        if (best < 0.4f)                lab = 0.0f;

        // box deltas from the argmax box (reciprocal muls; tol 3.92 >> ulp err)
        const float4 g = sbox[bb][bidx];
        const float gcx = (g.x + g.z) * 0.5f;
        const float gcy = (g.y + g.w) * 0.5f;
        const float tx = (gcx - acx) * ri.x;
        const float ty = (gcy - acy) * ri.y;
        const float tw = __logf((g.z - g.x) * ri.z) * 5.0f;   // /0.2
        const float th = __logf((g.w - g.y) * ri.w) * 5.0f;

        const size_t idx = (size_t)(b0 + bb) * A_TOTAL + a;
        ((float4*)out_loc)[idx] = make_float4(tx, ty, tw, th);
        out_cls[idx] = lab;
    }
}

extern "C" void kernel_launch(void* const* d_in, const int* in_sizes, int n_in,
                              void* d_out, int out_size, void* d_ws, size_t ws_size,
                              hipStream_t stream) {
    // inputs: f3..f6 (data unused; shapes compile-time), gt_boxes f32, gt_labels int
    const float* gt_boxes  = (const float*)d_in[4];
    const int*   gt_labels = (const int*)d_in[5];

    float4* rec = (float4*)d_ws;                    // 48960 * 16 B
    float4* rin = rec + A_TOTAL;                    // 48960 * 16 B
    float4* win = rin + A_TOTAL;                    // 765   * 16 B (~1.58 MB total)

    float* out_loc = (float*)d_out;                                  // (B, A, 4)
    float* out_cls = (float*)d_out + (size_t)B_BATCH * A_TOTAL * 4;  // (B, A)

    prep_kernel<<<(A_TOTAL + 255) / 256, 256, 0, stream>>>(rec, rin, win);

    dim3 grid((A_TOTAL + 255) / 256, B_BATCH / B_PER_BLK);   // 192 x 4 blocks
    anchors_assign_kernel<<<grid, 256, 0, stream>>>(gt_boxes, gt_labels,
                                                    rec, rin, win, out_loc, out_cls);
}

// Round 7
// 95.331 us; speedup vs baseline: 1.1927x; 1.1927x over previous
//
#include <hip/hip_runtime.h>
#include <math.h>

// Problem constants (from the reference):
//  levels: (64,64,s=8,bs=32) (32,32,s=16,bs=64) (16,16,s=32,bs=128) (8,8,s=64,bs=256)
//  K = 9 anchors/position (3 ratios x 3 scales), A = 48960, B = 16, M = 64 GT boxes
// Level boundaries 36864/46080/48384 are multiples of 64 -> every wave is
// single-level and every wave's 64 anchors share one bounding window.
// R6 lesson: the candidate walk is a latency-bound serial chain; batching
// batches per block (fewer waves, longer chains) regressed 91->114 us.
// R7: remove the latency instead - readlane replaces LDS in the walk.
#define A_TOTAL 48960
#define M_GT    64
#define B_BATCH 16

__device__ __forceinline__ float readlane_f(float v, int lane) {
    return __int_as_float(__builtin_amdgcn_readlane(__float_as_int(v), lane));
}

// ---- prep: batch-invariant per-anchor + per-wave data, computed once ----
// rec[a] = {acx, acy, aw, ah}; rin[a] = {1/(aw*.1), 1/(ah*.1), 1/aw, 1/ah};
// win[w] = {wx1, wy1, wx2, wy2} (exact per-wave bounding window)
__global__ __launch_bounds__(256) void prep_kernel(
    float4* __restrict__ rec, float4* __restrict__ rin, float4* __restrict__ win)
{
    const int a = blockIdx.x * 256 + threadIdx.x;
    if (a >= A_TOTAL) return;

    int local, W, stride, bs;
    if (a < 36864)      { local = a;         W = 64; stride = 8;  bs = 32;  }
    else if (a < 46080) { local = a - 36864; W = 32; stride = 16; bs = 64;  }
    else if (a < 48384) { local = a - 46080; W = 16; stride = 32; bs = 128; }
    else                { local = a - 48384; W = 8;  stride = 64; bs = 256; }

    const int hw = local / 9;
    const int k  = local - hw * 9;
    const int y  = hw / W;
    const int x  = hw - y * W;
    const int r  = k / 3;
    const int s  = k - r * 3;

    // anchor w/h in double, exactly mirroring numpy's op order
    const double sc = (s == 0) ? 1.0 : ((s == 1) ? 1.2599210498948732   // 2^(1/3)
                                                 : 1.5874010519681994); // 2^(2/3)
    const double rr = (r == 0) ? 0.5 : ((r == 1) ? 1.0 : 2.0);
    const double av   = (double)bs * sc;
    const double area = av * av;
    const double wd   = sqrt(area * rr);
    const double hd   = wd / rr;
    const float aw = (float)wd, ah = (float)hd;

    const float acx = ((float)x + 0.5f) * (float)stride;
    const float acy = ((float)y + 0.5f) * (float)stride;
    const float hx = aw * 0.5f, hy = ah * 0.5f;      // exact (*2^-1)
    const float ax1 = acx - hx, ay1 = acy - hy;
    const float ax2 = acx + hx, ay2 = acy + hy;

    rec[a] = make_float4(acx, acy, aw, ah);
    rin[a] = make_float4(1.0f / (aw * 0.1f), 1.0f / (ah * 0.1f),
                         1.0f / aw,          1.0f / ah);

    float wx1 = ax1, wy1 = ay1, wx2 = ax2, wy2 = ay2;
    #pragma unroll
    for (int m = 1; m < 64; m <<= 1) {
        wx1 = fminf(wx1, __shfl_xor(wx1, m, 64));
        wy1 = fminf(wy1, __shfl_xor(wy1, m, 64));
        wx2 = fmaxf(wx2, __shfl_xor(wx2, m, 64));
        wy2 = fmaxf(wy2, __shfl_xor(wy2, m, 64));
    }
    if ((threadIdx.x & 63) == 0) win[a >> 6] = make_float4(wx1, wy1, wx2, wy2);
}

__global__ __launch_bounds__(256) void anchors_assign_kernel(
    const float*  __restrict__ gt_boxes,   // (B, 64, 4) xyxy
    const int*    __restrict__ gt_labels,  // (B, 64)
    const float4* __restrict__ rec,
    const float4* __restrict__ rin,
    const float4* __restrict__ win,
    float* __restrict__ out_loc,           // (B, A, 4)
    float* __restrict__ out_cls)           // (B, A)
{
    __shared__ float4 sbox[M_GT];          // epilogue divergent gather only
    __shared__ float  slab[M_GT];

    const int b   = blockIdx.y;
    const int tid = threadIdx.x;
    const int lane = tid & 63;

    if (tid < M_GT) {
        const float4 g = ((const float4*)gt_boxes)[b * M_GT + tid];
        sbox[tid] = g;
        slab[tid] = (float)gt_labels[b * M_GT + tid];
    }
    __syncthreads();

    const int a = blockIdx.x * 256 + tid;
    if (a >= A_TOTAL) return;   // whole waves only (A_TOTAL % 64 == 0)

    // Per-lane GT box: lane holds box 'lane' in registers (L1-hit reload).
    const float4 gb = ((const float4*)gt_boxes)[b * M_GT + lane];
    const float garea = (gb.z - gb.x) * (gb.w - gb.y);   // same op order as ref

    // batch-invariant anchor data (L2-resident, coalesced float4 loads)
    const float4 rc = rec[a];
    const float4 ri = rin[a];
    const float4 wv = win[a >> 6];          // wave-uniform address -> 1 line

    const float acx = rc.x, acy = rc.y, aw = rc.z, ah = rc.w;
    const float hx = aw * 0.5f, hy = ah * 0.5f;    // bit-identical reconstruction
    const float ax1 = acx - hx, ay1 = acy - hy;
    const float ax2 = acx + hx, ay2 = acy + hy;
    const float areaA = (ax2 - ax1) * (ay2 - ay1); // ref recomputes from xyxy

    // Candidate mask: lane j tests GT box j against the wave window.
    // Edge-touching boxes give inter==0 for every anchor in the wave -> safe
    // to prune (0-iou can't beat b_inter=0 init; all-pruned -> bidx=0, which
    // equals np.argmax of an all-zero row).
    const bool cand = (fminf(wv.z, gb.z) > fmaxf(wv.x, gb.x)) &&
                      (fminf(wv.w, gb.w) > fmaxf(wv.y, gb.y));
    unsigned long long mask = __ballot(cand);   // wave-uniform

    // Division-free IoU argmax over candidates, ascending j (first max, as
    // np.argmax). j is wave-uniform -> box j comes from lane j's registers
    // via v_readlane (VALU pipe, ~4cyc) - NO memory ops in this loop.
    float b_inter = 0.0f, b_den = 1.0f;
    int   bidx = 0;
    while (mask) {
        const int j = (int)__builtin_ctzll(mask);
        mask &= mask - 1;
        const float gx = readlane_f(gb.x, j);
        const float gy = readlane_f(gb.y, j);
        const float gz = readlane_f(gb.z, j);
        const float gw = readlane_f(gb.w, j);
        const float ga = readlane_f(garea, j);
        const float ltx = fmaxf(ax1, gx), lty = fmaxf(ay1, gy);
        const float rbx = fminf(ax2, gz), rby = fminf(ay2, gw);
        const float wx = fmaxf(rbx - ltx, 0.0f);
        const float wy = fmaxf(rby - lty, 0.0f);
        const float inter = wx * wy;
        const float den   = (areaA + ga) - inter;   // same assoc as ref
        if (inter * b_den > b_inter * den) {        // iou_j > iou_best
            b_inter = inter; b_den = den; bidx = j;
        }
    }
    const float best = b_inter / b_den;   // exact IEEE: bit-matches ref's iou

    // label thresholding (order matches ref: ign first, bg overrides)
    float lab = slab[bidx];
    if (best > 0.4f && best < 0.5f) lab = -1.0f;
    if (best < 0.4f)                lab = 0.0f;

    // box deltas from the argmax box (reciprocal muls; tol 3.92 >> ulp err)
    const float4 g = sbox[bidx];
    const float gcx = (g.x + g.z) * 0.5f;
    const float gcy = (g.y + g.w) * 0.5f;
    const float tx = (gcx - acx) * ri.x;
    const float ty = (gcy - acy) * ri.y;
    const float tw = __logf((g.z - g.x) * ri.z) * 5.0f;   // /0.2
    const float th = __logf((g.w - g.y) * ri.w) * 5.0f;

    const size_t idx = (size_t)b * A_TOTAL + a;
    ((float4*)out_loc)[idx] = make_float4(tx, ty, tw, th);  // coalesced 16B store
    out_cls[idx] = lab;
}

extern "C" void kernel_launch(void* const* d_in, const int* in_sizes, int n_in,
                              void* d_out, int out_size, void* d_ws, size_t ws_size,
                              hipStream_t stream) {
    // inputs: f3..f6 (data unused; shapes compile-time), gt_boxes f32, gt_labels int
    const float* gt_boxes  = (const float*)d_in[4];
    const int*   gt_labels = (const int*)d_in[5];

    float4* rec = (float4*)d_ws;                    // 48960 * 16 B
    float4* rin = rec + A_TOTAL;                    // 48960 * 16 B
    float4* win = rin + A_TOTAL;                    // 765   * 16 B (~1.58 MB total)

    float* out_loc = (float*)d_out;                                  // (B, A, 4)
    float* out_cls = (float*)d_out + (size_t)B_BATCH * A_TOTAL * 4;  // (B, A)

    prep_kernel<<<(A_TOTAL + 255) / 256, 256, 0, stream>>>(rec, rin, win);

    dim3 grid((A_TOTAL + 255) / 256, B_BATCH);   // 192 x 16 blocks, 12 waves/SIMD
    anchors_assign_kernel<<<grid, 256, 0, stream>>>(gt_boxes, gt_labels,
                                                    rec, rin, win, out_loc, out_cls);
}

// Round 8
// 88.801 us; speedup vs baseline: 1.2804x; 1.0735x over previous
//
#include <hip/hip_runtime.h>
#include <math.h>

// Problem constants (from the reference):
//  levels: (64,64,s=8,bs=32) (32,32,s=16,bs=64) (16,16,s=32,bs=128) (8,8,s=64,bs=256)
//  K = 9 anchors/position (3 ratios x 3 scales), A = 48960, B = 16, M = 64 GT boxes
// Level boundaries 36864/46080/48384 are 64-aligned -> every wave is single-
// level and covers a contiguous hw range -> analytic conservative window.
// History: R5 (prep kernel + LDS walk) = 91.3us best; R6 batch-amortize
// regressed (latency-bound walk needs TLP); R7 readlane walk regressed
// (LDS latency was already hidden; readlane added VALU). R8 fuses prep away:
// 36-entry (aw,ah) LDS table built by spare staging threads (bit-exact f64,
// hidden behind the existing barrier), analytic window (no butterfly),
// single launch, no workspace.
#define A_TOTAL 48960
#define M_GT    64
#define B_BATCH 16

__global__ __launch_bounds__(256) void anchors_assign_kernel(
    const float* __restrict__ gt_boxes,   // (B, 64, 4) xyxy
    const int*   __restrict__ gt_labels,  // (B, 64)
    float* __restrict__ out_loc,          // (B, A, 4)
    float* __restrict__ out_cls)          // (B, A)
{
    __shared__ float4 sbox[M_GT];
    __shared__ float  sarea[M_GT];
    __shared__ float  slab[M_GT];
    __shared__ float2 swh[36];            // (aw, ah) per lvl*9+k, f64-exact cast

    const int b    = blockIdx.y;
    const int tid  = threadIdx.x;
    const int lane = tid & 63;

    if (tid < M_GT) {
        // Stage this batch's GT boxes (64 x float4 = 1 KiB)
        const float4 g = ((const float4*)gt_boxes)[b * M_GT + tid];
        sbox[tid]  = g;
        sarea[tid] = (g.z - g.x) * (g.w - g.y);   // same op order as ref
        slab[tid]  = (float)gt_labels[b * M_GT + tid];
    } else if (tid < M_GT + 36) {
        // Spare threads build the 36-entry anchor-wh table, bit-exact vs numpy:
        // a = bs*scale; area = a*a; w = sqrt(area*rr); h = w/rr; cast f32.
        // Cost hidden behind the staging barrier (runs in parallel with loads).
        const int t   = tid - M_GT;        // 0..35
        const int lvl = t / 9, k = t - lvl * 9;
        const int r   = k / 3, s = k - r * 3;
        const double sc = (s == 0) ? 1.0 : ((s == 1) ? 1.2599210498948732   // 2^(1/3)
                                                     : 1.5874010519681994); // 2^(2/3)
        const double rr = (r == 0) ? 0.5 : ((r == 1) ? 1.0 : 2.0);
        const double bs   = (double)(32 << lvl);
        const double av   = bs * sc;
        const double area = av * av;
        const double wd   = sqrt(area * rr);
        swh[t] = make_float2((float)wd, (float)(wd / rr));
    }
    __syncthreads();

    const int a = blockIdx.x * 256 + tid;
    if (a >= A_TOTAL) return;   // tail is whole waves, after the barrier

    // ---- decode anchor index (cheap: shifts + one magic-div by 9) ----
    int local, lgW, lvl;
    if (a < 36864)      { local = a;         lgW = 6; lvl = 0; }
    else if (a < 46080) { local = a - 36864; lgW = 5; lvl = 1; }
    else if (a < 48384) { local = a - 46080; lgW = 4; lvl = 2; }
    else                { local = a - 48384; lgW = 3; lvl = 3; }
    const float stride_f = (float)(8 << lvl);

    const int hw = local / 9;              // magic-mul
    const int k  = local - hw * 9;
    const int y  = hw >> lgW;
    const int x  = hw & ((1 << lgW) - 1);

    const float2 wh = swh[lvl * 9 + k];    // 9 distinct addrs/wave -> ~no conflict
    const float aw = wh.x, ah = wh.y;
    const float acx = ((float)x + 0.5f) * stride_f;   // exact, same form as ref
    const float acy = ((float)y + 0.5f) * stride_f;
    const float hx = aw * 0.5f, hy = ah * 0.5f;
    const float ax1 = acx - hx, ay1 = acy - hy;
    const float ax2 = acx + hx, ay2 = acy + hy;
    const float areaA = (ax2 - ax1) * (ay2 - ay1);    // ref recomputes from xyxy

    // ---- analytic conservative wave window (wave-uniform values) ----
    // Wave's anchors are local indices [l0, l0+63] at one level; centers span
    // [hw0, hw1]; half-extent bound bs*1.1225 >= bs*2^(2/3)*sqrt(2)/2 (max
    // aw/2 = max ah/2). A window containing the exact union is safe: any
    // pruned box has inter==0 with every anchor here, and 0-iou can't win
    // under strict '>' with b_inter=0 init (all-pruned -> bidx=0 = np.argmax
    // of an all-zero row). So labels/targets are bit-identical to full scan.
    const int l0  = local - lane;
    const int hw0 = l0 / 9;
    const int hw1 = (l0 + 63) / 9;
    const int y0  = hw0 >> lgW, y1 = hw1 >> lgW;
    int x0, x1;
    if (y0 == y1) { x0 = hw0 & ((1 << lgW) - 1); x1 = hw1 & ((1 << lgW) - 1); }
    else          { x0 = 0;                      x1 = (1 << lgW) - 1;         }
    const float margin = (float)(32 << lvl) * 1.1225f;
    const float wx1 = ((float)x0 + 0.5f) * stride_f - margin;
    const float wx2 = ((float)x1 + 0.5f) * stride_f + margin;
    const float wy1 = ((float)y0 + 0.5f) * stride_f - margin;
    const float wy2 = ((float)y1 + 0.5f) * stride_f + margin;

    // ---- candidate mask: lane j tests GT box j against the wave window ----
    const float4 gb = sbox[lane];
    const bool cand = (fminf(wx2, gb.z) > fmaxf(wx1, gb.x)) &&
                      (fminf(wy2, gb.w) > fmaxf(wy1, gb.y));
    unsigned long long mask = __ballot(cand);   // wave-uniform

    // ---- division-free IoU argmax over candidates, ascending j ----
    // iou_j > iou_best <=> inter_j*den_best > inter_best*den_j (dens > 0);
    // strict '>' keeps the first max, matching np.argmax. Uniform j -> LDS
    // broadcast; latency hidden by 12 waves/SIMD TLP (R6/R7 lessons).
    float b_inter = 0.0f, b_den = 1.0f;
    int   bidx = 0;
    while (mask) {
        const int j = (int)__builtin_ctzll(mask);
        mask &= mask - 1;
        const float4 g = sbox[j];
        const float ltx = fmaxf(ax1, g.x), lty = fmaxf(ay1, g.y);
        const float rbx = fminf(ax2, g.z), rby = fminf(ay2, g.w);
        const float wx = fmaxf(rbx - ltx, 0.0f);
        const float wy = fmaxf(rby - lty, 0.0f);
        const float inter = wx * wy;
        const float den   = (areaA + sarea[j]) - inter;   // same assoc as ref
        if (inter * b_den > b_inter * den) {
            b_inter = inter; b_den = den; bidx = j;
        }
    }
    const float best = b_inter / b_den;   // exact IEEE: bit-matches ref's iou

    // ---- label thresholding (order matches ref: ign first, bg overrides) ----
    float lab = slab[bidx];
    if (best > 0.4f && best < 0.5f) lab = -1.0f;
    if (best < 0.4f)                lab = 0.0f;

    // ---- box deltas (v_rcp muls; loc-only error ~1e-6 << tol 3.92) ----
    const float4 g = sbox[bidx];
    const float rcw = __builtin_amdgcn_rcpf(aw);
    const float rch = __builtin_amdgcn_rcpf(ah);
    const float gcx = (g.x + g.z) * 0.5f;
    const float gcy = (g.y + g.w) * 0.5f;
    const float tx = (gcx - acx) * rcw * 10.0f;        // /(aw*0.1)
    const float ty = (gcy - acy) * rch * 10.0f;
    const float tw = __logf((g.z - g.x) * rcw) * 5.0f; // /0.2
    const float th = __logf((g.w - g.y) * rch) * 5.0f;

    const size_t idx = (size_t)b * A_TOTAL + a;
    ((float4*)out_loc)[idx] = make_float4(tx, ty, tw, th);  // coalesced 16B store
    out_cls[idx] = lab;
}

extern "C" void kernel_launch(void* const* d_in, const int* in_sizes, int n_in,
                              void* d_out, int out_size, void* d_ws, size_t ws_size,
                              hipStream_t stream) {
    // inputs: f3..f6 (data unused; shapes compile-time), gt_boxes f32, gt_labels int
    const float* gt_boxes  = (const float*)d_in[4];
    const int*   gt_labels = (const int*)d_in[5];

    float* out_loc = (float*)d_out;                                  // (B, A, 4)
    float* out_cls = (float*)d_out + (size_t)B_BATCH * A_TOTAL * 4;  // (B, A)

    dim3 grid((A_TOTAL + 255) / 256, B_BATCH);   // 192 x 16 blocks, single launch
    anchors_assign_kernel<<<grid, 256, 0, stream>>>(gt_boxes, gt_labels,
                                                    out_loc, out_cls);
}